// Round 1
// baseline (347.309 us; speedup 1.0000x reference)
//
#include <hip/hip_runtime.h>
#include <math.h>

// ---------------------------------------------------------------------------
// GCN 3-layer forward: gcn_norm (self-loops, sym D^-1/2) + 3x (GEMM -> CSR
// aggregate) with fused bias/ReLU and final log-softmax.
// ---------------------------------------------------------------------------

// ---- CSR build -------------------------------------------------------------

__global__ __launch_bounds__(256) void hist_kernel(const int* __restrict__ col,
                                                   int* __restrict__ counts, int e) {
  int i = blockIdx.x * 256 + threadIdx.x;
  if (i < e) atomicAdd(&counts[col[i]], 1);
}

// single-block chunked Hillis-Steele scan: offsets[0]=0, offsets[i+1]=sum counts[0..i]
__global__ __launch_bounds__(1024) void scan_kernel(const int* __restrict__ counts,
                                                    int* __restrict__ offsets, int n) {
  __shared__ int lds[1024];
  __shared__ int carry_s;
  int tid = threadIdx.x;
  if (tid == 0) carry_s = 0;
  __syncthreads();
  for (int base = 0; base < n; base += 1024) {
    int i = base + tid;
    int v = (i < n) ? counts[i] : 0;
    lds[tid] = v;
    __syncthreads();
    for (int off = 1; off < 1024; off <<= 1) {
      int t = (tid >= off) ? lds[tid - off] : 0;
      __syncthreads();
      lds[tid] += t;
      __syncthreads();
    }
    int incl = lds[tid];
    int carry = carry_s;
    if (i < n) offsets[i + 1] = carry + incl;
    __syncthreads();
    if (tid == 1023) carry_s = carry + incl;
    __syncthreads();
  }
  if (tid == 0) offsets[0] = 0;
}

__global__ __launch_bounds__(256) void dinv_kernel(const int* __restrict__ counts,
                                                   float* __restrict__ dinv, int n) {
  int i = blockIdx.x * 256 + threadIdx.x;
  if (i < n) dinv[i] = rsqrtf((float)(counts[i] + 1));  // +1 self-loop
}

// pack (row, norm) per edge into int2, grouped by destination
__global__ __launch_bounds__(256) void fill_kernel(const int* __restrict__ row,
                                                   const int* __restrict__ col,
                                                   const int* __restrict__ offsets,
                                                   int* __restrict__ cursor,
                                                   const float* __restrict__ dinv,
                                                   int2* __restrict__ csr, int e) {
  int i = blockIdx.x * 256 + threadIdx.x;
  if (i < e) {
    int c = col[i], r = row[i];
    int pos = offsets[c] + atomicAdd(&cursor[c], 1);
    float nrm = dinv[r] * dinv[c];
    csr[pos] = make_int2(r, __float_as_int(nrm));
  }
}

// ---- dense GEMM: Y[n][F] = X[n][K] @ W[K][F] (no bias; added in aggregate) --

template <int K, int F>
__global__ __launch_bounds__(256) void gemm_kernel(const float* __restrict__ X,
                                                   const float* __restrict__ W,
                                                   float* __restrict__ Y, int n) {
  __shared__ float xs[16][K];
  int tid = threadIdx.x;
  int node0 = blockIdx.x * 16;
  for (int i = tid; i < 16 * K; i += 256) {
    int nd = node0 + i / K;
    xs[i / K][i % K] = (nd < n) ? X[(size_t)nd * K + (i % K)] : 0.f;
  }
  __syncthreads();
  int g = tid >> 6, lane = tid & 63;
  if (lane < F) {
    float acc0 = 0.f, acc1 = 0.f, acc2 = 0.f, acc3 = 0.f;
#pragma unroll 8
    for (int k = 0; k < K; ++k) {
      float w = W[k * F + lane];
      acc0 += xs[g * 4 + 0][k] * w;
      acc1 += xs[g * 4 + 1][k] * w;
      acc2 += xs[g * 4 + 2][k] * w;
      acc3 += xs[g * 4 + 3][k] * w;
    }
    float accs[4] = {acc0, acc1, acc2, acc3};
#pragma unroll
    for (int j = 0; j < 4; ++j) {
      int nd = node0 + g * 4 + j;
      if (nd < n) Y[(size_t)nd * F + lane] = accs[j];
    }
  }
}

// ---- aggregate: one wave per node, feature-per-lane ------------------------
// MODE 0: bias + ReLU.  MODE 1: bias + log_softmax over F (=40) features.

template <int F, int MODE>
__global__ __launch_bounds__(256) void agg_kernel(const float* __restrict__ H,
                                                  const int2* __restrict__ csr,
                                                  const int* __restrict__ offsets,
                                                  const float* __restrict__ dinv,
                                                  const float* __restrict__ bias,
                                                  float* __restrict__ Y, int n) {
  int wave = (blockIdx.x * 256 + threadIdx.x) >> 6;
  int lane = threadIdx.x & 63;
  if (wave >= n) return;
  float di = dinv[wave];
  float acc = 0.f;
  if (lane < F) acc = H[(size_t)wave * F + lane] * di * di;  // self-loop
  int s = offsets[wave], e = offsets[wave + 1];
  int i = s;
  for (; i + 4 <= e; i += 4) {
    int2 p0 = csr[i], p1 = csr[i + 1], p2 = csr[i + 2], p3 = csr[i + 3];
    if (lane < F) {
      float h0 = H[(size_t)p0.x * F + lane];
      float h1 = H[(size_t)p1.x * F + lane];
      float h2 = H[(size_t)p2.x * F + lane];
      float h3 = H[(size_t)p3.x * F + lane];
      acc += h0 * __int_as_float(p0.y) + h1 * __int_as_float(p1.y) +
             h2 * __int_as_float(p2.y) + h3 * __int_as_float(p3.y);
    }
  }
  for (; i < e; ++i) {
    int2 p = csr[i];
    if (lane < F) acc += H[(size_t)p.x * F + lane] * __int_as_float(p.y);
  }
  if (MODE == 0) {
    if (lane < F) {
      float v = acc + bias[lane];
      Y[(size_t)wave * F + lane] = v > 0.f ? v : 0.f;
    }
  } else {
    float v = (lane < F) ? acc + bias[lane] : -INFINITY;
    float m = v;
#pragma unroll
    for (int off = 32; off; off >>= 1) m = fmaxf(m, __shfl_xor(m, off));
    float ex = (lane < F) ? expf(v - m) : 0.f;
    float ssum = ex;
#pragma unroll
    for (int off = 32; off; off >>= 1) ssum += __shfl_xor(ssum, off);
    if (lane < F) Y[(size_t)wave * F + lane] = v - m - logf(ssum);
  }
}

// ---------------------------------------------------------------------------

extern "C" void kernel_launch(void* const* d_in, const int* in_sizes, int n_in,
                              void* d_out, int out_size, void* d_ws, size_t ws_size,
                              hipStream_t stream) {
  const float* x  = (const float*)d_in[0];
  const int*   ei = (const int*)d_in[1];
  const float* W1 = (const float*)d_in[2];
  const float* b1 = (const float*)d_in[3];
  const float* W2 = (const float*)d_in[4];
  const float* b2 = (const float*)d_in[5];
  const float* W3 = (const float*)d_in[6];
  const float* b3 = (const float*)d_in[7];
  float* out = (float*)d_out;

  const int N = in_sizes[0] / 128;
  const int E = in_sizes[1] / 2;
  const int* erow = ei;       // edge_index[0] = source
  const int* ecol = ei + E;   // edge_index[1] = target

  // workspace carve (256B-aligned)
  auto align_up = [](size_t v) { return (v + 255) & ~(size_t)255; };
  char* ws = (char*)d_ws;
  size_t off = 0;
  int* counts   = (int*)(ws + off); off += align_up((size_t)N * 4 * 2);  // counts+cursor contiguous
  int* cursor   = counts + N;       // lives inside the region above
  int* offsets  = (int*)(ws + off); off += align_up((size_t)(N + 1) * 4);
  float* dinv   = (float*)(ws + off); off += align_up((size_t)N * 4);
  int2* csr     = (int2*)(ws + off); off += align_up((size_t)E * 8);
  float* bufA   = (float*)(ws + off); off += align_up((size_t)N * 64 * 4);
  float* bufB   = (float*)(ws + off); off += align_up((size_t)N * 64 * 4);
  (void)ws_size;

  // zero counts + cursor (contiguous 2N ints)
  hipMemsetAsync(counts, 0, (size_t)N * 4 * 2, stream);

  const int eb = (E + 255) / 256;
  const int nb = (N + 255) / 256;

  hist_kernel<<<eb, 256, 0, stream>>>(ecol, counts, E);
  scan_kernel<<<1, 1024, 0, stream>>>(counts, offsets, N);
  dinv_kernel<<<nb, 256, 0, stream>>>(counts, dinv, N);
  fill_kernel<<<eb, 256, 0, stream>>>(erow, ecol, offsets, cursor, dinv, csr, E);

  const int gemm_blocks = (N + 15) / 16;
  const int agg_blocks = (N + 3) / 4;  // 4 waves (nodes) per 256-thread block

  // layer 1: x(128) @ W1 -> 64, aggregate, +b1, ReLU
  gemm_kernel<128, 64><<<gemm_blocks, 256, 0, stream>>>(x, W1, bufA, N);
  agg_kernel<64, 0><<<agg_blocks, 256, 0, stream>>>(bufA, csr, offsets, dinv, b1, bufB, N);

  // layer 2: h(64) @ W2 -> 64, aggregate, +b2, ReLU
  gemm_kernel<64, 64><<<gemm_blocks, 256, 0, stream>>>(bufB, W2, bufA, N);
  agg_kernel<64, 0><<<agg_blocks, 256, 0, stream>>>(bufA, csr, offsets, dinv, b2, bufB, N);

  // layer 3: h(64) @ W3 -> 40, aggregate, +b3, log_softmax
  gemm_kernel<64, 40><<<gemm_blocks, 256, 0, stream>>>(bufB, W3, bufA, N);
  agg_kernel<40, 1><<<agg_blocks, 256, 0, stream>>>(bufA, csr, offsets, dinv, b3, out, N);
}

// Round 2
// 342.016 us; speedup vs baseline: 1.0155x; 1.0155x over previous
//
#include <hip/hip_runtime.h>
#include <math.h>

// ---------------------------------------------------------------------------
// GCN 3-layer forward: gcn_norm (self-loops, sym D^-1/2) + 3x (GEMM -> CSR
// aggregate) with fused bias/ReLU and final log-softmax.
// R2: fast thread-sequential scan (+fused dinv), shfl-broadcast CSR in agg
// with 8-wide gather unroll for memory-level parallelism.
// ---------------------------------------------------------------------------

__global__ __launch_bounds__(256) void hist_kernel(const int* __restrict__ col,
                                                   int* __restrict__ counts, int e) {
  int i = blockIdx.x * 256 + threadIdx.x;
  if (i < e) atomicAdd(&counts[col[i]], 1);
}

// Single block. offsets[i] = exclusive prefix of counts, offsets[n] = total.
// dinv[i] = rsqrt(counts[i] + 1)  (+1 = self loop).
__global__ __launch_bounds__(1024) void scan_kernel(const int* __restrict__ counts,
                                                    int* __restrict__ offsets,
                                                    float* __restrict__ dinv, int n) {
  __shared__ int part[1024];
  int tid = threadIdx.x;
  int chunk = (n + 1023) >> 10;
  int s = tid * chunk;
  int e = s + chunk < n ? s + chunk : n;
  int sum = 0;
  for (int i = s; i < e; ++i) sum += counts[i];
  part[tid] = sum;
  __syncthreads();
#pragma unroll
  for (int off = 1; off < 1024; off <<= 1) {
    int t = (tid >= off) ? part[tid - off] : 0;
    __syncthreads();
    part[tid] += t;
    __syncthreads();
  }
  int run = (tid == 0) ? 0 : part[tid - 1];
  for (int i = s; i < e; ++i) {
    int c = counts[i];
    offsets[i] = run;
    dinv[i] = rsqrtf((float)(c + 1));
    run += c;
  }
  if (tid == 0) offsets[n] = part[1023];
}

// pack (row, norm) per edge into int2, grouped by destination
__global__ __launch_bounds__(256) void fill_kernel(const int* __restrict__ row,
                                                   const int* __restrict__ col,
                                                   const int* __restrict__ offsets,
                                                   int* __restrict__ cursor,
                                                   const float* __restrict__ dinv,
                                                   int2* __restrict__ csr, int e) {
  int i = blockIdx.x * 256 + threadIdx.x;
  if (i < e) {
    int c = col[i], r = row[i];
    int pos = offsets[c] + atomicAdd(&cursor[c], 1);
    float nrm = dinv[r] * dinv[c];
    csr[pos] = make_int2(r, __float_as_int(nrm));
  }
}

// ---- dense GEMM: Y[n][F] = X[n][K] @ W[K][F] (no bias; added in aggregate) --

template <int K, int F>
__global__ __launch_bounds__(256) void gemm_kernel(const float* __restrict__ X,
                                                   const float* __restrict__ W,
                                                   float* __restrict__ Y, int n) {
  __shared__ float xs[16][K];
  int tid = threadIdx.x;
  int node0 = blockIdx.x * 16;
  // float4 staging of 16 rows x K cols
  constexpr int KV = K / 4;
  const float4* X4 = (const float4*)X;
  for (int i = tid; i < 16 * KV; i += 256) {
    int r = i / KV, c = i % KV;
    int nd = node0 + r;
    float4 v = make_float4(0.f, 0.f, 0.f, 0.f);
    if (nd < n) v = X4[(size_t)nd * KV + c];
    ((float4*)&xs[r][0])[c] = v;
  }
  __syncthreads();
  int g = tid >> 6, lane = tid & 63;
  if (lane < F) {
    float acc0 = 0.f, acc1 = 0.f, acc2 = 0.f, acc3 = 0.f;
#pragma unroll 8
    for (int k = 0; k < K; ++k) {
      float w = W[k * F + lane];
      acc0 += xs[g * 4 + 0][k] * w;
      acc1 += xs[g * 4 + 1][k] * w;
      acc2 += xs[g * 4 + 2][k] * w;
      acc3 += xs[g * 4 + 3][k] * w;
    }
    float accs[4] = {acc0, acc1, acc2, acc3};
#pragma unroll
    for (int j = 0; j < 4; ++j) {
      int nd = node0 + g * 4 + j;
      if (nd < n) Y[(size_t)nd * F + lane] = accs[j];
    }
  }
}

// ---- aggregate: one wave per node, feature-per-lane ------------------------
// CSR entries for the node are loaded once as a coalesced 64-wide load and
// broadcast via shfl (wave-uniform index -> readlane + scalar-base gathers).
// MODE 0: bias + ReLU.  MODE 1: bias + log_softmax over F (=40) features.

template <int F, int MODE>
__global__ __launch_bounds__(256) void agg_kernel(const float* __restrict__ H,
                                                  const int2* __restrict__ csr,
                                                  const int* __restrict__ offsets,
                                                  const float* __restrict__ dinv,
                                                  const float* __restrict__ bias,
                                                  float* __restrict__ Y, int n) {
  constexpr bool FULL = (F == 64);
  int wave = (blockIdx.x * 256 + threadIdx.x) >> 6;
  int lane = threadIdx.x & 63;
  if (wave >= n) return;
  float di = dinv[wave];
  int s = offsets[wave], e = offsets[wave + 1];
  float acc = 0.f;
  if (FULL || lane < F) acc = H[(size_t)wave * F + lane] * (di * di);  // self-loop

  for (int base = s; base < e; base += 64) {
    int rem = e - base;
    int cnt = rem < 64 ? rem : 64;
    int2 p = csr[base + (lane < cnt ? lane : 0)];  // one coalesced 512B load
    int j = 0;
    for (; j + 8 <= cnt; j += 8) {
      int r0 = __shfl(p.x, j + 0), r1 = __shfl(p.x, j + 1);
      int r2 = __shfl(p.x, j + 2), r3 = __shfl(p.x, j + 3);
      int r4 = __shfl(p.x, j + 4), r5 = __shfl(p.x, j + 5);
      int r6 = __shfl(p.x, j + 6), r7 = __shfl(p.x, j + 7);
      float w0 = __int_as_float(__shfl(p.y, j + 0));
      float w1 = __int_as_float(__shfl(p.y, j + 1));
      float w2 = __int_as_float(__shfl(p.y, j + 2));
      float w3 = __int_as_float(__shfl(p.y, j + 3));
      float w4 = __int_as_float(__shfl(p.y, j + 4));
      float w5 = __int_as_float(__shfl(p.y, j + 5));
      float w6 = __int_as_float(__shfl(p.y, j + 6));
      float w7 = __int_as_float(__shfl(p.y, j + 7));
      if (FULL || lane < F) {
        float h0 = H[(size_t)r0 * F + lane];
        float h1 = H[(size_t)r1 * F + lane];
        float h2 = H[(size_t)r2 * F + lane];
        float h3 = H[(size_t)r3 * F + lane];
        float h4 = H[(size_t)r4 * F + lane];
        float h5 = H[(size_t)r5 * F + lane];
        float h6 = H[(size_t)r6 * F + lane];
        float h7 = H[(size_t)r7 * F + lane];
        acc += h0 * w0; acc += h1 * w1; acc += h2 * w2; acc += h3 * w3;
        acc += h4 * w4; acc += h5 * w5; acc += h6 * w6; acc += h7 * w7;
      }
    }
    for (; j < cnt; ++j) {
      int r = __shfl(p.x, j);
      float w = __int_as_float(__shfl(p.y, j));
      if (FULL || lane < F) acc += H[(size_t)r * F + lane] * w;
    }
  }

  if (MODE == 0) {
    if (FULL || lane < F) {
      float v = acc + bias[lane];
      Y[(size_t)wave * F + lane] = v > 0.f ? v : 0.f;
    }
  } else {
    float v = (lane < F) ? acc + bias[lane] : -INFINITY;
    float m = v;
#pragma unroll
    for (int off = 32; off; off >>= 1) m = fmaxf(m, __shfl_xor(m, off));
    float ex = (lane < F) ? expf(v - m) : 0.f;
    float ssum = ex;
#pragma unroll
    for (int off = 32; off; off >>= 1) ssum += __shfl_xor(ssum, off);
    if (lane < F) Y[(size_t)wave * F + lane] = v - m - logf(ssum);
  }
}

// ---------------------------------------------------------------------------

extern "C" void kernel_launch(void* const* d_in, const int* in_sizes, int n_in,
                              void* d_out, int out_size, void* d_ws, size_t ws_size,
                              hipStream_t stream) {
  const float* x  = (const float*)d_in[0];
  const int*   ei = (const int*)d_in[1];
  const float* W1 = (const float*)d_in[2];
  const float* b1 = (const float*)d_in[3];
  const float* W2 = (const float*)d_in[4];
  const float* b2 = (const float*)d_in[5];
  const float* W3 = (const float*)d_in[6];
  const float* b3 = (const float*)d_in[7];
  float* out = (float*)d_out;

  const int N = in_sizes[0] / 128;
  const int E = in_sizes[1] / 2;
  const int* erow = ei;       // edge_index[0] = source
  const int* ecol = ei + E;   // edge_index[1] = target

  auto align_up = [](size_t v) { return (v + 255) & ~(size_t)255; };
  char* ws = (char*)d_ws;
  size_t off = 0;
  int* counts   = (int*)(ws + off); off += align_up((size_t)N * 4 * 2);
  int* cursor   = counts + N;  // contiguous with counts for one memset
  int* offsets  = (int*)(ws + off); off += align_up((size_t)(N + 1) * 4);
  float* dinv   = (float*)(ws + off); off += align_up((size_t)N * 4);
  int2* csr     = (int2*)(ws + off); off += align_up((size_t)E * 8);
  float* bufA   = (float*)(ws + off); off += align_up((size_t)N * 64 * 4);
  float* bufB   = (float*)(ws + off); off += align_up((size_t)N * 64 * 4);
  (void)ws_size;

  hipMemsetAsync(counts, 0, (size_t)N * 4 * 2, stream);

  const int eb = (E + 255) / 256;

  hist_kernel<<<eb, 256, 0, stream>>>(ecol, counts, E);
  scan_kernel<<<1, 1024, 0, stream>>>(counts, offsets, dinv, N);
  fill_kernel<<<eb, 256, 0, stream>>>(erow, ecol, offsets, cursor, dinv, csr, E);

  const int gemm_blocks = (N + 15) / 16;
  const int agg_blocks = (N + 3) / 4;  // 4 waves (nodes) per 256-thread block

  gemm_kernel<128, 64><<<gemm_blocks, 256, 0, stream>>>(x, W1, bufA, N);
  agg_kernel<64, 0><<<agg_blocks, 256, 0, stream>>>(bufA, csr, offsets, dinv, b1, bufB, N);

  gemm_kernel<64, 64><<<gemm_blocks, 256, 0, stream>>>(bufB, W2, bufA, N);
  agg_kernel<64, 0><<<agg_blocks, 256, 0, stream>>>(bufA, csr, offsets, dinv, b2, bufB, N);

  gemm_kernel<64, 40><<<gemm_blocks, 256, 0, stream>>>(bufB, W3, bufA, N);
  agg_kernel<40, 1><<<agg_blocks, 256, 0, stream>>>(bufA, csr, offsets, dinv, b3, out, N);
}

// Round 3
// 245.680 us; speedup vs baseline: 1.4137x; 1.3921x over previous
//
#include <hip/hip_runtime.h>
#include <math.h>

// ---------------------------------------------------------------------------
// GCN 3-layer forward: gcn_norm (self-loops, sym D^-1/2) + 3x (GEMM -> CSR
// aggregate) with fused bias/ReLU and final log-softmax.
// R3: hierarchical 3-kernel scan (blocksum -> wave scan -> scanwrite+dinv)
// replacing the single-block 108us scan.
// ---------------------------------------------------------------------------

__global__ __launch_bounds__(256) void hist_kernel(const int* __restrict__ col,
                                                   int* __restrict__ counts, int e) {
  int i = blockIdx.x * 256 + threadIdx.x;
  if (i < e) atomicAdd(&counts[col[i]], 1);
}

// ---- hierarchical scan ------------------------------------------------------

__global__ __launch_bounds__(256) void blocksum_kernel(const int* __restrict__ counts,
                                                       int* __restrict__ partials, int n) {
  __shared__ int lds[256];
  int tid = threadIdx.x;
  int gid = blockIdx.x * 256 + tid;
  lds[tid] = (gid < n) ? counts[gid] : 0;
  __syncthreads();
  for (int off = 128; off; off >>= 1) {
    if (tid < off) lds[tid] += lds[tid + off];
    __syncthreads();
  }
  if (tid == 0) partials[blockIdx.x] = lds[0];
}

// single wave: in-place exclusive scan of partials[nb], nb <= 256
__global__ __launch_bounds__(64) void scanpart_kernel(int* __restrict__ partials, int nb) {
  int lane = threadIdx.x;
  int v0 = 0, v1 = 0, v2 = 0, v3 = 0;
  int s = lane * 4;
  if (s + 0 < nb) v0 = partials[s + 0];
  if (s + 1 < nb) v1 = partials[s + 1];
  if (s + 2 < nb) v2 = partials[s + 2];
  if (s + 3 < nb) v3 = partials[s + 3];
  int sum = v0 + v1 + v2 + v3;
  int run = sum;
#pragma unroll
  for (int off = 1; off < 64; off <<= 1) {
    int t = __shfl_up(run, off);
    if (lane >= off) run += t;
  }
  int excl = run - sum;  // exclusive prefix of this lane's chunk
  if (s + 0 < nb) partials[s + 0] = excl;
  excl += v0;
  if (s + 1 < nb) partials[s + 1] = excl;
  excl += v1;
  if (s + 2 < nb) partials[s + 2] = excl;
  excl += v2;
  if (s + 3 < nb) partials[s + 3] = excl;
}

// per-block LDS scan + scanned block base; writes exclusive offsets and dinv.
__global__ __launch_bounds__(256) void scanwrite_kernel(const int* __restrict__ counts,
                                                        const int* __restrict__ partials,
                                                        int* __restrict__ offsets,
                                                        float* __restrict__ dinv, int n) {
  __shared__ int lds[256];
  int tid = threadIdx.x;
  int gid = blockIdx.x * 256 + tid;
  int v = (gid < n) ? counts[gid] : 0;
  lds[tid] = v;
  __syncthreads();
#pragma unroll
  for (int off = 1; off < 256; off <<= 1) {
    int t = (tid >= off) ? lds[tid - off] : 0;
    __syncthreads();
    lds[tid] += t;
    __syncthreads();
  }
  int incl = lds[tid];
  int base = partials[blockIdx.x];
  if (gid < n) {
    offsets[gid] = base + incl - v;
    dinv[gid] = rsqrtf((float)(v + 1));
    if (gid == n - 1) offsets[n] = base + incl;
  }
}

// pack (row, norm) per edge into int2, grouped by destination
__global__ __launch_bounds__(256) void fill_kernel(const int* __restrict__ row,
                                                   const int* __restrict__ col,
                                                   const int* __restrict__ offsets,
                                                   int* __restrict__ cursor,
                                                   const float* __restrict__ dinv,
                                                   int2* __restrict__ csr, int e) {
  int i = blockIdx.x * 256 + threadIdx.x;
  if (i < e) {
    int c = col[i], r = row[i];
    int pos = offsets[c] + atomicAdd(&cursor[c], 1);
    float nrm = dinv[r] * dinv[c];
    csr[pos] = make_int2(r, __float_as_int(nrm));
  }
}

// ---- dense GEMM: Y[n][F] = X[n][K] @ W[K][F] (no bias; added in aggregate) --

template <int K, int F>
__global__ __launch_bounds__(256) void gemm_kernel(const float* __restrict__ X,
                                                   const float* __restrict__ W,
                                                   float* __restrict__ Y, int n) {
  __shared__ float xs[16][K];
  int tid = threadIdx.x;
  int node0 = blockIdx.x * 16;
  constexpr int KV = K / 4;
  const float4* X4 = (const float4*)X;
  for (int i = tid; i < 16 * KV; i += 256) {
    int r = i / KV, c = i % KV;
    int nd = node0 + r;
    float4 v = make_float4(0.f, 0.f, 0.f, 0.f);
    if (nd < n) v = X4[(size_t)nd * KV + c];
    ((float4*)&xs[r][0])[c] = v;
  }
  __syncthreads();
  int g = tid >> 6, lane = tid & 63;
  if (lane < F) {
    float acc0 = 0.f, acc1 = 0.f, acc2 = 0.f, acc3 = 0.f;
#pragma unroll 8
    for (int k = 0; k < K; ++k) {
      float w = W[k * F + lane];
      acc0 += xs[g * 4 + 0][k] * w;
      acc1 += xs[g * 4 + 1][k] * w;
      acc2 += xs[g * 4 + 2][k] * w;
      acc3 += xs[g * 4 + 3][k] * w;
    }
    float accs[4] = {acc0, acc1, acc2, acc3};
#pragma unroll
    for (int j = 0; j < 4; ++j) {
      int nd = node0 + g * 4 + j;
      if (nd < n) Y[(size_t)nd * F + lane] = accs[j];
    }
  }
}

// ---- aggregate: one wave per node, feature-per-lane ------------------------
// CSR entries for the node are loaded once as a coalesced 64-wide load and
// broadcast via shfl; 8-wide gather unroll for memory-level parallelism.
// MODE 0: bias + ReLU.  MODE 1: bias + log_softmax over F (=40) features.

template <int F, int MODE>
__global__ __launch_bounds__(256) void agg_kernel(const float* __restrict__ H,
                                                  const int2* __restrict__ csr,
                                                  const int* __restrict__ offsets,
                                                  const float* __restrict__ dinv,
                                                  const float* __restrict__ bias,
                                                  float* __restrict__ Y, int n) {
  constexpr bool FULL = (F == 64);
  int wave = (blockIdx.x * 256 + threadIdx.x) >> 6;
  int lane = threadIdx.x & 63;
  if (wave >= n) return;
  float di = dinv[wave];
  int s = offsets[wave], e = offsets[wave + 1];
  float acc = 0.f;
  if (FULL || lane < F) acc = H[(size_t)wave * F + lane] * (di * di);  // self-loop

  for (int base = s; base < e; base += 64) {
    int rem = e - base;
    int cnt = rem < 64 ? rem : 64;
    int2 p = csr[base + (lane < cnt ? lane : 0)];  // one coalesced 512B load
    int j = 0;
    for (; j + 8 <= cnt; j += 8) {
      int r0 = __shfl(p.x, j + 0), r1 = __shfl(p.x, j + 1);
      int r2 = __shfl(p.x, j + 2), r3 = __shfl(p.x, j + 3);
      int r4 = __shfl(p.x, j + 4), r5 = __shfl(p.x, j + 5);
      int r6 = __shfl(p.x, j + 6), r7 = __shfl(p.x, j + 7);
      float w0 = __int_as_float(__shfl(p.y, j + 0));
      float w1 = __int_as_float(__shfl(p.y, j + 1));
      float w2 = __int_as_float(__shfl(p.y, j + 2));
      float w3 = __int_as_float(__shfl(p.y, j + 3));
      float w4 = __int_as_float(__shfl(p.y, j + 4));
      float w5 = __int_as_float(__shfl(p.y, j + 5));
      float w6 = __int_as_float(__shfl(p.y, j + 6));
      float w7 = __int_as_float(__shfl(p.y, j + 7));
      if (FULL || lane < F) {
        float h0 = H[(size_t)r0 * F + lane];
        float h1 = H[(size_t)r1 * F + lane];
        float h2 = H[(size_t)r2 * F + lane];
        float h3 = H[(size_t)r3 * F + lane];
        float h4 = H[(size_t)r4 * F + lane];
        float h5 = H[(size_t)r5 * F + lane];
        float h6 = H[(size_t)r6 * F + lane];
        float h7 = H[(size_t)r7 * F + lane];
        acc += h0 * w0; acc += h1 * w1; acc += h2 * w2; acc += h3 * w3;
        acc += h4 * w4; acc += h5 * w5; acc += h6 * w6; acc += h7 * w7;
      }
    }
    for (; j < cnt; ++j) {
      int r = __shfl(p.x, j);
      float w = __int_as_float(__shfl(p.y, j));
      if (FULL || lane < F) acc += H[(size_t)r * F + lane] * w;
    }
  }

  if (MODE == 0) {
    if (FULL || lane < F) {
      float v = acc + bias[lane];
      Y[(size_t)wave * F + lane] = v > 0.f ? v : 0.f;
    }
  } else {
    float v = (lane < F) ? acc + bias[lane] : -INFINITY;
    float m = v;
#pragma unroll
    for (int off = 32; off; off >>= 1) m = fmaxf(m, __shfl_xor(m, off));
    float ex = (lane < F) ? expf(v - m) : 0.f;
    float ssum = ex;
#pragma unroll
    for (int off = 32; off; off >>= 1) ssum += __shfl_xor(ssum, off);
    if (lane < F) Y[(size_t)wave * F + lane] = v - m - logf(ssum);
  }
}

// ---------------------------------------------------------------------------

extern "C" void kernel_launch(void* const* d_in, const int* in_sizes, int n_in,
                              void* d_out, int out_size, void* d_ws, size_t ws_size,
                              hipStream_t stream) {
  const float* x  = (const float*)d_in[0];
  const int*   ei = (const int*)d_in[1];
  const float* W1 = (const float*)d_in[2];
  const float* b1 = (const float*)d_in[3];
  const float* W2 = (const float*)d_in[4];
  const float* b2 = (const float*)d_in[5];
  const float* W3 = (const float*)d_in[6];
  const float* b3 = (const float*)d_in[7];
  float* out = (float*)d_out;

  const int N = in_sizes[0] / 128;
  const int E = in_sizes[1] / 2;
  const int* erow = ei;       // edge_index[0] = source
  const int* ecol = ei + E;   // edge_index[1] = target

  auto align_up = [](size_t v) { return (v + 255) & ~(size_t)255; };
  char* ws = (char*)d_ws;
  size_t off = 0;
  int* counts   = (int*)(ws + off); off += align_up((size_t)N * 4 * 2);
  int* cursor   = counts + N;  // contiguous with counts for one memset
  int* offsets  = (int*)(ws + off); off += align_up((size_t)(N + 1) * 4);
  float* dinv   = (float*)(ws + off); off += align_up((size_t)N * 4);
  int* partials = (int*)(ws + off); off += align_up(256 * 4);
  int2* csr     = (int2*)(ws + off); off += align_up((size_t)E * 8);
  float* bufA   = (float*)(ws + off); off += align_up((size_t)N * 64 * 4);
  float* bufB   = (float*)(ws + off); off += align_up((size_t)N * 64 * 4);
  (void)ws_size;

  hipMemsetAsync(counts, 0, (size_t)N * 4 * 2, stream);

  const int eb = (E + 255) / 256;
  const int nb = (N + 255) / 256;  // 196 <= 256, required by scanpart_kernel

  hist_kernel<<<eb, 256, 0, stream>>>(ecol, counts, E);
  blocksum_kernel<<<nb, 256, 0, stream>>>(counts, partials, N);
  scanpart_kernel<<<1, 64, 0, stream>>>(partials, nb);
  scanwrite_kernel<<<nb, 256, 0, stream>>>(counts, partials, offsets, dinv, N);
  fill_kernel<<<eb, 256, 0, stream>>>(erow, ecol, offsets, cursor, dinv, csr, E);

  const int gemm_blocks = (N + 15) / 16;
  const int agg_blocks = (N + 3) / 4;  // 4 waves (nodes) per 256-thread block

  gemm_kernel<128, 64><<<gemm_blocks, 256, 0, stream>>>(x, W1, bufA, N);
  agg_kernel<64, 0><<<agg_blocks, 256, 0, stream>>>(bufA, csr, offsets, dinv, b1, bufB, N);

  gemm_kernel<64, 64><<<gemm_blocks, 256, 0, stream>>>(bufB, W2, bufA, N);
  agg_kernel<64, 0><<<agg_blocks, 256, 0, stream>>>(bufA, csr, offsets, dinv, b2, bufB, N);

  gemm_kernel<64, 40><<<gemm_blocks, 256, 0, stream>>>(bufB, W3, bufA, N);
  agg_kernel<40, 1><<<agg_blocks, 256, 0, stream>>>(bufA, csr, offsets, dinv, b3, out, N);
}